// Round 7
// baseline (102.316 us; speedup 1.0000x reference)
//
#include <hip/hip_runtime.h>

// ---------------------------------------------------------------------------
// Chamfer_Loss: chamfer(pred,tgt) + W_EDGE*edge + W_LAP*cotLap + W_NORMAL*nc
//               + W_VEL*chamfer(diff(pred), diff(tgt))
// B=2, N=8281 (g=91), fp32 in/out. Output: 1 scalar.
// R7: chamfer via MFMA (32x32x16 bf16, hi/lo split for fp32-grade precision).
//     K-slots fold the constant terms so acc_u = yy - 2x.y and
//     acc_v = xx - 2x.y come straight out of the matrix op; post-proc is
//     pure v_min. Both chamfer directions from one tile sweep (work halved).
//     VALU formulation plateaued at ~58us across R4-R6 (~53% of op model).
// ---------------------------------------------------------------------------

typedef unsigned int uint32;
typedef __attribute__((ext_vector_type(8)))  short bf16x8;
typedef __attribute__((ext_vector_type(16))) float f32x16;

#define W_EDGE   0.5f
#define W_LAP    0.05f
#define W_NORMAL 0.01f
#define W_VEL    10.0f
#define BIGF     3.0e38f
#define RSTRIDE  8320      // padded row/col stride (>= 8281, 8320 = 65*128)

__device__ __forceinline__ unsigned short f2bf(float f){
    uint32 b = __float_as_uint(f);
    b += 0x7FFFu + ((b >> 16) & 1u);          // RNE
    return (unsigned short)(b >> 16);
}
__device__ __forceinline__ float bf2f(unsigned short h){
    return __uint_as_float(((uint32)h) << 16);
}
// monotone float<->uint key (handles negatives) for atomicMin
__device__ __forceinline__ uint32 fkey(float f){
    uint32 b = __float_as_uint(f);
    return b ^ ((uint32)((int)b >> 31) | 0x80000000u);
}
__device__ __forceinline__ float funkey(uint32 k){
    uint32 b = (k & 0x80000000u) ? (k ^ 0x80000000u) : ~k;
    return __uint_as_float(b);
}

__device__ __forceinline__ float wave_sum(float v) {
#pragma unroll
    for (int o = 32; o > 0; o >>= 1) v += __shfl_down(v, o, 64);
    return v;
}

// Zero [accum | Lx | rowsum]; set colmin keys to 0xFFFFFFFF (=+inf key).
__global__ void init_ws_k(float* __restrict__ ws, int nzero, int ninf)
{
    uint32* w = (uint32*)ws;
    const int total = nzero + ninf;
    for (int i = blockIdx.x * blockDim.x + threadIdx.x; i < total;
         i += gridDim.x * blockDim.x)
        w[i] = (i < nzero) ? 0u : 0xFFFFFFFFu;
}

// ---------------------------------------------------------------------------
// B-fragment prep: one wave per (combo, y-tile). combo c: ds=c>>1 (0 main,
// 1 vel-diff), b=c&1. Emits two bf16x8 frags per lane (Bu for acc_u, Bv for
// acc_v). K-slot map (A-side listed for reference):
//  k0-2 : A=-2xh  B=yh     k3-5 : A=-2xl B=yh   k6-8 : A=-2xh B=yl
//  k9   : A=xxh   Bv=1 Bu=0      k10 : A=xxl  Bv=1 Bu=0
//  k11  : A=1     Bu=yyh Bv=0    k12 : A=1    Bu=yyl Bv=0    k13-15: 0
// Lane l: col = l&31, holds k = (l>>5)*8 + i.
// ---------------------------------------------------------------------------
__global__ void bprep_k(const float* __restrict__ tgt, int N, uint4* __restrict__ bfrag)
{
    const int NT = (N + 31) >> 5;
    const int gt = blockIdx.x * 4 + (threadIdx.x >> 6);
    if (gt >= 4 * NT) return;
    const int c = gt / NT, t = gt - c * NT;
    const int ds = c >> 1, b = c & 1;
    const int Np = N - ds;
    const int l = threadIdx.x & 63;
    const int col = t * 32 + (l & 31);
    const float* __restrict__ yb = tgt + (size_t)b * N * 3;
    float y0 = 0.f, y1 = 0.f, y2 = 0.f;
    const bool valid = col < Np;
    if (valid){
        if (ds){
            y0 = yb[(col+1)*3+0] - yb[col*3+0];
            y1 = yb[(col+1)*3+1] - yb[col*3+1];
            y2 = yb[(col+1)*3+2] - yb[col*3+2];
        } else {
            y0 = yb[col*3+0]; y1 = yb[col*3+1]; y2 = yb[col*3+2];
        }
    }
    const float yy = fmaf(y0,y0, fmaf(y1,y1, y2*y2));
    unsigned short yh0=f2bf(y0), yh1=f2bf(y1), yh2=f2bf(y2);
    unsigned short yl0=f2bf(y0-bf2f(yh0)), yl1=f2bf(y1-bf2f(yh1)), yl2=f2bf(y2-bf2f(yh2));
    unsigned short yyh, yyl;
    if (valid){ yyh = f2bf(yy); yyl = f2bf(yy - bf2f(yyh)); }
    else      { yyh = f2bf(BIGF); yyl = 0; }   // pad col: u huge (never min)
    const short ONE = (short)0x3F80;
    bf16x8 Bu, Bv;
    if (l < 32){        // k0-7
        Bu[0]=(short)yh0; Bu[1]=(short)yh1; Bu[2]=(short)yh2;
        Bu[3]=(short)yh0; Bu[4]=(short)yh1; Bu[5]=(short)yh2;
        Bu[6]=(short)yl0; Bu[7]=(short)yl1;
        Bv = Bu;
    } else {            // k8-15
        Bu[0]=(short)yl2; Bu[1]=0;   Bu[2]=0;   Bu[3]=(short)yyh; Bu[4]=(short)yyl;
        Bu[5]=0; Bu[6]=0; Bu[7]=0;
        Bv[0]=(short)yl2; Bv[1]=ONE; Bv[2]=ONE; Bv[3]=0;          Bv[4]=0;
        Bv[5]=0; Bv[6]=0; Bv[7]=0;
    }
    const size_t base = (size_t)(c * NT + t) * 128 + l;
    bfrag[base]      = __builtin_bit_cast(uint4, Bu);
    bfrag[base + 64] = __builtin_bit_cast(uint4, Bv);
}

// ---------------------------------------------------------------------------
// MFMA chamfer: grid (xblocks=65, ychunks=4, combos=4), 256 thr (4 waves).
// Wave w owns rows xb*128 + w*32 .. +31; sweeps its y-chunk's tiles.
// acc_u[r] = yy[col] - 2 dot -> row-min in regs (rowpart, per chunk, no atomics)
// acc_v[r] = xx[row] - 2 dot -> col-min via reg tree + LDS + global key atomic
// ---------------------------------------------------------------------------
__global__ __launch_bounds__(256)
void chamfer_mfma_k(const float* __restrict__ pred, int N,
                    const uint4* __restrict__ bfrag,
                    float* __restrict__ rowpart, uint32* __restrict__ colmin)
{
    const int c = blockIdx.z, ds = c >> 1, b = c & 1;
    const int Np = N - ds;
    const int NT = (N + 31) >> 5;            // 259 for N=8281
    const int TC = (NT + 3) >> 2;            // 65 tiles per chunk
    const int t0 = blockIdx.y * TC;
    const int t1 = min(NT, t0 + TC);
    const int w = threadIdx.x >> 6, l = threadIdx.x & 63;
    const int h = l >> 5;
    const int grow = blockIdx.x * 128 + w * 32 + (l & 31);

    const float* __restrict__ xb = pred + (size_t)b * N * 3;
    float a0 = 0.f, a1 = 0.f, a2 = 0.f;
    const bool xvalid = grow < Np;
    if (xvalid){
        if (ds){
            a0 = xb[(grow+1)*3+0] - xb[grow*3+0];
            a1 = xb[(grow+1)*3+1] - xb[grow*3+1];
            a2 = xb[(grow+1)*3+2] - xb[grow*3+2];
        } else {
            a0 = xb[grow*3+0]; a1 = xb[grow*3+1]; a2 = xb[grow*3+2];
        }
    }
    const float xx = fmaf(a0,a0, fmaf(a1,a1, a2*a2));
    unsigned short xh0=f2bf(a0), xh1=f2bf(a1), xh2=f2bf(a2);
    unsigned short nxh0=f2bf(-2.f*bf2f(xh0)), nxh1=f2bf(-2.f*bf2f(xh1)), nxh2=f2bf(-2.f*bf2f(xh2));
    unsigned short nxl0=f2bf(-2.f*(a0-bf2f(xh0))), nxl1=f2bf(-2.f*(a1-bf2f(xh1))),
                   nxl2=f2bf(-2.f*(a2-bf2f(xh2)));
    const float xxf = xvalid ? xx : BIGF;     // pad row: v huge for col-min
    unsigned short xxh=f2bf(xxf), xxl=f2bf(xxf-bf2f(xxh));
    const short ONE = (short)0x3F80;
    bf16x8 A;
    if (h == 0){   // k0-7
        A[0]=(short)nxh0; A[1]=(short)nxh1; A[2]=(short)nxh2;
        A[3]=(short)nxl0; A[4]=(short)nxl1; A[5]=(short)nxl2;
        A[6]=(short)nxh0; A[7]=(short)nxh1;
    } else {       // k8-15
        A[0]=(short)nxh2; A[1]=(short)xxh; A[2]=(short)xxl;
        A[3]=ONE; A[4]=ONE; A[5]=0; A[6]=0; A[7]=0;
    }

    // xx lookup per C-layout row (fp32, for final rowmin = xx + min(u))
    const float xxst = xvalid ? xx : 0.f;
    float xxr[16];
#pragma unroll
    for (int r = 0; r < 16; ++r)
        xxr[r] = __shfl(xxst, (r&3) + 8*(r>>2) + 4*h, 64);

    __shared__ uint32 cl[2080];               // TC*32 = 2080 for N=8281
    for (int i = threadIdx.x; i < TC*32; i += 256) cl[i] = 0xFFFFFFFFu;
    __syncthreads();

    float rm[16];
#pragma unroll
    for (int r = 0; r < 16; ++r) rm[r] = BIGF;
    f32x16 zacc;
#pragma unroll
    for (int r = 0; r < 16; ++r) zacc[r] = 0.f;

    const uint4* __restrict__ bfp = bfrag + (size_t)c * NT * 128 + l;

    for (int t = t0; t < t1; ++t){
        const bf16x8 Bu = __builtin_bit_cast(bf16x8, bfp[(size_t)t*128]);
        const bf16x8 Bv = __builtin_bit_cast(bf16x8, bfp[(size_t)t*128 + 64]);
        const f32x16 au = __builtin_amdgcn_mfma_f32_32x32x16_bf16(A, Bu, zacc, 0, 0, 0);
        const f32x16 av = __builtin_amdgcn_mfma_f32_32x32x16_bf16(A, Bv, zacc, 0, 0, 0);
#pragma unroll
        for (int r = 0; r < 16; ++r) rm[r] = fminf(rm[r], au[r]);
        float cv = fminf(fminf(av[0],  av[1]),  av[2]);       // -> v_min3 chain
        cv = fminf(fminf(cv, av[3]),  av[4]);
        cv = fminf(fminf(cv, av[5]),  av[6]);
        cv = fminf(fminf(cv, av[7]),  av[8]);
        cv = fminf(fminf(cv, av[9]),  av[10]);
        cv = fminf(fminf(cv, av[11]), av[12]);
        cv = fminf(fminf(cv, av[13]), av[14]);
        cv = fminf(cv, av[15]);
        cv = fminf(cv, __shfl_xor(cv, 32, 64));               // combine halves (same col)
        if (l < 32) atomicMin(&cl[(t - t0)*32 + l], fkey(cv));
    }

    // row-min butterfly within each 32-lane half (cols live across lanes)
#pragma unroll
    for (int r = 0; r < 16; ++r){
        float v = rm[r];
        v = fminf(v, __shfl_xor(v, 1, 64));
        v = fminf(v, __shfl_xor(v, 2, 64));
        v = fminf(v, __shfl_xor(v, 4, 64));
        v = fminf(v, __shfl_xor(v, 8, 64));
        v = fminf(v, __shfl_xor(v, 16, 64));
        rm[r] = v;
    }
    float* __restrict__ rp = rowpart + (size_t)(c*4 + blockIdx.y) * RSTRIDE;
#pragma unroll
    for (int r = 0; r < 16; ++r){             // static index only (no scratch)
        if ((l & 31) == r){
            const int rowl = (r&3) + 8*(r>>2) + 4*h;
            const int gr = blockIdx.x * 128 + w * 32 + rowl;
            if (gr < Np) rp[gr] = rm[r] + xxr[r];
        }
    }

    __syncthreads();
    const int ncols = (t1 - t0) * 32;
    uint32* __restrict__ cm = colmin + (size_t)c * RSTRIDE;
    for (int i = threadIdx.x; i < ncols; i += 256){
        const int col = t0*32 + i;
        if (col < Np) atomicMin(&cm[col], cl[i]);
    }
}

// edge loss + normal consistency + laplacian cot scatter, one dispatch.
__global__ void mesh_k(const float* __restrict__ pred,
                       const int* __restrict__ edges, int E,
                       const int* __restrict__ pairs, int P,
                       const int* __restrict__ faces, int F,
                       int N, int B, float scaleE, float scaleP,
                       float* __restrict__ Lx, float* __restrict__ rowsum,
                       float* __restrict__ accum)
{
    const int tE = B * E, tP = B * P, tF = B * F;
    const int total = tE + tP + tF;
    float se = 0.f, sp = 0.f;
    for (int idx = blockIdx.x * blockDim.x + threadIdx.x; idx < total;
         idx += gridDim.x * blockDim.x) {
        if (idx < tE) {
            const int b = idx / E;
            const int e = idx - b * E;
            const float* __restrict__ vb = pred + (size_t)b * N * 3;
            const int i0 = edges[e * 2 + 0], i1 = edges[e * 2 + 1];
            float dx = vb[i0 * 3 + 0] - vb[i1 * 3 + 0];
            float dy = vb[i0 * 3 + 1] - vb[i1 * 3 + 1];
            float dz = vb[i0 * 3 + 2] - vb[i1 * 3 + 2];
            se += fmaf(dx, dx, fmaf(dy, dy, dz * dz));
        } else if (idx < tE + tP) {
            const int q = idx - tE;
            const int b = q / P;
            const int p = q - b * P;
            const float* __restrict__ vb = pred + (size_t)b * N * 3;
            const int a0 = pairs[p * 4 + 0], a1 = pairs[p * 4 + 1];
            const int a2 = pairs[p * 4 + 2], a3 = pairs[p * 4 + 3];
            float p0x = vb[a0 * 3], p0y = vb[a0 * 3 + 1], p0z = vb[a0 * 3 + 2];
            float ex = vb[a1 * 3] - p0x, ey = vb[a1 * 3 + 1] - p0y, ez = vb[a1 * 3 + 2] - p0z;
            float ux = vb[a2 * 3] - p0x, uy = vb[a2 * 3 + 1] - p0y, uz = vb[a2 * 3 + 2] - p0z;
            float wx = vb[a3 * 3] - p0x, wy = vb[a3 * 3 + 1] - p0y, wz = vb[a3 * 3 + 2] - p0z;
            float n0x = ey * uz - ez * uy;
            float n0y = ez * ux - ex * uz;
            float n0z = ex * uy - ey * ux;
            float n1x = -(ey * wz - ez * wy);
            float n1y = -(ez * wx - ex * wz);
            float n1z = -(ex * wy - ey * wx);
            float dt = n0x * n1x + n0y * n1y + n0z * n1z;
            float l0 = sqrtf(n0x * n0x + n0y * n0y + n0z * n0z);
            float l1 = sqrtf(n1x * n1x + n1y * n1y + n1z * n1z);
            sp += 1.0f - dt / (fmaxf(l0, 1e-8f) * fmaxf(l1, 1e-8f));
        } else {
            const int q = idx - tE - tP;
            const int b = q / F;
            const int f = q - b * F;
            const float* __restrict__ vb = pred + (size_t)b * N * 3;
            const int i0 = faces[f * 3 + 0], i1 = faces[f * 3 + 1], i2 = faces[f * 3 + 2];
            float v0x = vb[i0 * 3], v0y = vb[i0 * 3 + 1], v0z = vb[i0 * 3 + 2];
            float v1x = vb[i1 * 3], v1y = vb[i1 * 3 + 1], v1z = vb[i1 * 3 + 2];
            float v2x = vb[i2 * 3], v2y = vb[i2 * 3 + 1], v2z = vb[i2 * 3 + 2];
            float ax = v1x - v2x, ay = v1y - v2y, az = v1z - v2z;
            float bx = v0x - v2x, by = v0y - v2y, bz = v0z - v2z;
            float cx = v0x - v1x, cy = v0y - v1y, cz = v0z - v1z;
            float A  = sqrtf(ax * ax + ay * ay + az * az);
            float Bl = sqrtf(bx * bx + by * by + bz * bz);
            float C  = sqrtf(cx * cx + cy * cy + cz * cz);
            float s2 = 0.5f * (A + Bl + C);
            float area = sqrtf(fmaxf(s2 * (s2 - A) * (s2 - Bl) * (s2 - C), 1e-12f));
            float A2 = A * A, B2 = Bl * Bl, C2 = C * C;
            float inv4a = 1.0f / (4.0f * area);
            float cota = (B2 + C2 - A2) * inv4a;
            float cotb = (A2 + C2 - B2) * inv4a;
            float cotc = (A2 + B2 - C2) * inv4a;

            float* __restrict__ Lb = Lx + (size_t)b * N * 3;
            float* __restrict__ rb = rowsum + (size_t)b * N;
            #define SCAT(i, j, wv)                                            \
                atomicAdd(&Lb[(i) * 3 + 0], (wv) * vb[(j) * 3 + 0]);          \
                atomicAdd(&Lb[(i) * 3 + 1], (wv) * vb[(j) * 3 + 1]);          \
                atomicAdd(&Lb[(i) * 3 + 2], (wv) * vb[(j) * 3 + 2]);          \
                atomicAdd(&rb[(i)], (wv));
            SCAT(i1, i2, cota) SCAT(i2, i1, cota)
            SCAT(i2, i0, cotb) SCAT(i0, i2, cotb)
            SCAT(i0, i1, cotc) SCAT(i1, i0, cotc)
            #undef SCAT
        }
    }
    se = wave_sum(se);
    sp = wave_sum(sp);
    if ((threadIdx.x & 63) == 0) atomicAdd(accum, fmaf(se, scaleE, sp * scaleP));
}

// rowpart min-reduce + colmin (+yy) + lap residual, one dispatch.
__global__ void finalize_k(const float* __restrict__ rowpart, const uint32* __restrict__ colmin,
                           const float* __restrict__ tgt, const float* __restrict__ pred,
                           const float* __restrict__ Lx, const float* __restrict__ rowsum,
                           int N, float sMain, float sVel, float scaleL,
                           float* __restrict__ accum)
{
    const int total = 8 * N + 2 * N;
    float sm = 0.f, sv = 0.f, sl = 0.f;
    for (int idx = blockIdx.x * blockDim.x + threadIdx.x; idx < total;
         idx += gridDim.x * blockDim.x) {
        if (idx < 4 * N) {
            const int c = idx / N, i = idx - c * N;
            const int ds = c >> 1;
            if (i < N - ds) {
                const float* rp = rowpart + (size_t)c * 4 * RSTRIDE;
                float v = fminf(fminf(rp[i], rp[RSTRIDE + i]),
                                fminf(rp[2*RSTRIDE + i], rp[3*RSTRIDE + i]));
                float d = fmaxf(v, 0.f);
                if (ds) sv += d; else sm += d;
            }
        } else if (idx < 8 * N) {
            const int q = idx - 4 * N;
            const int c = q / N, j = q - c * N;
            const int ds = c >> 1, b = c & 1;
            if (j < N - ds) {
                const float* __restrict__ yb = tgt + (size_t)b * N * 3;
                float y0, y1, y2;
                if (ds) {
                    y0 = yb[(j+1)*3+0] - yb[j*3+0];
                    y1 = yb[(j+1)*3+1] - yb[j*3+1];
                    y2 = yb[(j+1)*3+2] - yb[j*3+2];
                } else { y0 = yb[j*3+0]; y1 = yb[j*3+1]; y2 = yb[j*3+2]; }
                float yy = fmaf(y0,y0, fmaf(y1,y1, y2*y2));
                float v = funkey(colmin[(size_t)c * RSTRIDE + j]) + yy;
                float d = fmaxf(v, 0.f);
                if (ds) sv += d; else sm += d;
            }
        } else {
            const int q = idx - 8 * N;       // B*N lap entries
            float rs = rowsum[q];
            float nw = rs > 0.f ? 1.0f / rs : 0.f;
            float rx = Lx[q*3+0]*nw - pred[q*3+0];
            float ry = Lx[q*3+1]*nw - pred[q*3+1];
            float rz = Lx[q*3+2]*nw - pred[q*3+2];
            sl += sqrtf(rx*rx + ry*ry + rz*rz);
        }
    }
    sm = wave_sum(sm); sv = wave_sum(sv); sl = wave_sum(sl);
    if ((threadIdx.x & 63) == 0)
        atomicAdd(accum, fmaf(sm, sMain, fmaf(sv, sVel, sl * scaleL)));
}

__global__ void write_out_k(const float* __restrict__ accum, float* __restrict__ out)
{
    out[0] = accum[0];
}

extern "C" void kernel_launch(void* const* d_in, const int* in_sizes, int n_in,
                              void* d_out, int out_size, void* d_ws, size_t ws_size,
                              hipStream_t stream)
{
    const float* pred = (const float*)d_in[0];
    const float* tgt  = (const float*)d_in[1];
    const int* faces  = (const int*)d_in[2];
    const int* edges  = (const int*)d_in[3];
    const int* pairs  = (const int*)d_in[4];

    const int B = 2;
    const int N = in_sizes[0] / (3 * B);   // 8281
    const int F = in_sizes[2] / 3;
    const int E = in_sizes[3] / 2;
    const int P = in_sizes[4] / 4;
    const int NT = (N + 31) >> 5;          // 259

    // workspace layout (4B units):
    // [accum 8][Lx B*N*3][rowsum B*N][colmin 4*RSTRIDE u32][rowpart 16*RSTRIDE][bfrag]
    float* ws      = (float*)d_ws;
    float* accum   = ws;
    float* Lx      = ws + 8;
    float* rowsum  = Lx + (size_t)B * N * 3;
    uint32* colmin = (uint32*)(rowsum + (size_t)B * N);
    float* rowpart = (float*)(colmin + 4 * RSTRIDE);
    size_t off     = 8 + (size_t)B*N*3 + (size_t)B*N + 4*RSTRIDE + 16*RSTRIDE;
    uint4* bfrag   = (uint4*)(ws + off);   // off*4 is 16B-aligned for N=8281

    const int nzero = 8 + B * N * 3 + B * N;
    const int ninf  = 4 * RSTRIDE;

    init_ws_k<<<64, dim3(256), 0, stream>>>(ws, nzero, ninf);

    bprep_k<<<dim3(NT), dim3(256), 0, stream>>>(tgt, N, bfrag);

    chamfer_mfma_k<<<dim3((N + 127) / 128, 4, 4), dim3(256), 0, stream>>>(
        pred, N, bfrag, rowpart, colmin);

    mesh_k<<<128, dim3(256), 0, stream>>>(pred, edges, E, pairs, P, faces, F, N, B,
                                          W_EDGE / ((float)B * (float)E),
                                          W_NORMAL / ((float)B * (float)P),
                                          Lx, rowsum, accum);

    finalize_k<<<96, dim3(256), 0, stream>>>(rowpart, colmin, tgt, pred, Lx, rowsum, N,
                                             1.0f / ((float)B * (float)N),
                                             W_VEL / ((float)B * (float)(N - 1)),
                                             W_LAP / ((float)B * (float)N), accum);

    write_out_k<<<1, 1, 0, stream>>>(accum, (float*)d_out);
}

// Round 8
// 98.506 us; speedup vs baseline: 1.0387x; 1.0387x over previous
//
#include <hip/hip_runtime.h>

// ---------------------------------------------------------------------------
// Chamfer_Loss: chamfer(pred,tgt) + W_EDGE*edge + W_LAP*cotLap + W_NORMAL*nc
//               + W_VEL*chamfer(diff(pred), diff(tgt))
// B=2, N=8281 (g=91), fp32 in/out. Output: 1 scalar.
// R8: row-min-only MFMA chamfer, two sweeps (dir 0/1), d fully folded into
//     the accumulator (xx via A k9/k10 x B=1). Post-proc per 32x32x2 tiles:
//     16 v_min3 only. No LDS, no atomics, no col machinery (R7's 60% VALUBusy
//     was C-reg extraction + min-tree + AGPR moves).
// ---------------------------------------------------------------------------

typedef unsigned int uint32;
typedef __attribute__((ext_vector_type(8)))  short bf16x8;
typedef __attribute__((ext_vector_type(16))) float f32x16;

#define W_EDGE   0.5f
#define W_LAP    0.05f
#define W_NORMAL 0.01f
#define W_VEL    10.0f
#define BIGF     3.0e38f
#define RSTRIDE  8320      // padded row stride (>= 8281, 8320 = 65*128)

__device__ __forceinline__ unsigned short f2bf(float f){
    uint32 b = __float_as_uint(f);
    b += 0x7FFFu + ((b >> 16) & 1u);          // RNE
    return (unsigned short)(b >> 16);
}
__device__ __forceinline__ float bf2f(unsigned short h){
    return __uint_as_float(((uint32)h) << 16);
}

__device__ __forceinline__ float wave_sum(float v) {
#pragma unroll
    for (int o = 32; o > 0; o >>= 1) v += __shfl_down(v, o, 64);
    return v;
}

// Zero [accum | Lx | rowsum].
__global__ void init_ws_k(float* __restrict__ ws, int nzero)
{
    uint32* w = (uint32*)ws;
    for (int i = blockIdx.x * blockDim.x + threadIdx.x; i < nzero;
         i += gridDim.x * blockDim.x)
        w[i] = 0u;
}

// ---------------------------------------------------------------------------
// B-fragment prep: one wave per (combo, y-tile).
// combo c = dir*4 + ds*2 + b; dir 0: y-side = tgt, dir 1: y-side = pred;
// ds: 0 main, 1 velocity-diff; b: batch.
// K-slot map (A-side in chamfer kernel):
//  k0-2: A=-2xh B=yh | k3-5: A=-2xl B=yh | k6-8: A=-2xh B=yl
//  k9:   A=xxh  B=1  | k10:  A=xxl B=1  | k11: A=1 B=yyh | k12: A=1 B=yyl
//  k13-15: 0.   acc = xx + yy - 2 x.y = d  (pad col: yy=BIG => never min)
// Lane l: col = l&31, holds k = (l>>5)*8 + i.
// ---------------------------------------------------------------------------
__global__ void bprep_k(const float* __restrict__ pred, const float* __restrict__ tgt,
                        int N, uint4* __restrict__ bfrag)
{
    const int NT = (N + 31) >> 5;
    const int gt = blockIdx.x * 4 + (threadIdx.x >> 6);
    if (gt >= 8 * NT) return;
    const int c = gt / NT, t = gt - c * NT;
    const int dir = c >> 2, ds = (c >> 1) & 1, b = c & 1;
    const int Np = N - ds;
    const int l = threadIdx.x & 63;
    const int col = t * 32 + (l & 31);
    const float* __restrict__ yb = (dir ? pred : tgt) + (size_t)b * N * 3;
    float y0 = 0.f, y1 = 0.f, y2 = 0.f;
    const bool valid = col < Np;
    if (valid){
        if (ds){
            y0 = yb[(col+1)*3+0] - yb[col*3+0];
            y1 = yb[(col+1)*3+1] - yb[col*3+1];
            y2 = yb[(col+1)*3+2] - yb[col*3+2];
        } else {
            y0 = yb[col*3+0]; y1 = yb[col*3+1]; y2 = yb[col*3+2];
        }
    }
    const float yy = fmaf(y0,y0, fmaf(y1,y1, y2*y2));
    unsigned short yh0=f2bf(y0), yh1=f2bf(y1), yh2=f2bf(y2);
    unsigned short yl0=f2bf(y0-bf2f(yh0)), yl1=f2bf(y1-bf2f(yh1)), yl2=f2bf(y2-bf2f(yh2));
    unsigned short yyh, yyl;
    if (valid){ yyh = f2bf(yy); yyl = f2bf(yy - bf2f(yyh)); }
    else      { yyh = f2bf(BIGF); yyl = 0; }
    const short ONE = (short)0x3F80;
    bf16x8 Bu;
    if (l < 32){        // k0-7
        Bu[0]=(short)yh0; Bu[1]=(short)yh1; Bu[2]=(short)yh2;
        Bu[3]=(short)yh0; Bu[4]=(short)yh1; Bu[5]=(short)yh2;
        Bu[6]=(short)yl0; Bu[7]=(short)yl1;
    } else {            // k8-15
        Bu[0]=(short)yl2; Bu[1]=ONE; Bu[2]=ONE; Bu[3]=(short)yyh; Bu[4]=(short)yyl;
        Bu[5]=0; Bu[6]=0; Bu[7]=0;
    }
    bfrag[(size_t)(c * NT + t) * 64 + l] = __builtin_bit_cast(uint4, Bu);
}

// ---------------------------------------------------------------------------
// MFMA chamfer, row-min only. grid (65 x-blocks, 4 y-chunks, 8 combos),
// 256 thr = 4 waves; wave w owns rows bx*128 + w*32..+31, sweeps its chunk's
// tiles in pairs (2 independent MFMAs -> 16 v_min3).
// rowpart[c][chunk][row] = min_{cols in chunk} d(row, col)
// ---------------------------------------------------------------------------
__global__ __launch_bounds__(256)
void chamfer_mfma_k(const float* __restrict__ pred, const float* __restrict__ tgt,
                    int N, const uint4* __restrict__ bfrag,
                    float* __restrict__ rowpart)
{
    const int c = blockIdx.z;
    const int dir = c >> 2, ds = (c >> 1) & 1, b = c & 1;
    const int Np = N - ds;
    const int NT = (N + 31) >> 5;            // 259
    const int TC = (NT + 3) >> 2;            // 65
    const int t0 = blockIdx.y * TC;
    const int t1 = min(NT, t0 + TC);
    const int w = threadIdx.x >> 6, l = threadIdx.x & 63;
    const int h = l >> 5;
    const int grow = blockIdx.x * 128 + w * 32 + (l & 31);

    const float* __restrict__ xb = (dir ? tgt : pred) + (size_t)b * N * 3;
    float a0 = 0.f, a1 = 0.f, a2 = 0.f;
    const bool xvalid = grow < Np;
    if (xvalid){
        if (ds){
            a0 = xb[(grow+1)*3+0] - xb[grow*3+0];
            a1 = xb[(grow+1)*3+1] - xb[grow*3+1];
            a2 = xb[(grow+1)*3+2] - xb[grow*3+2];
        } else {
            a0 = xb[grow*3+0]; a1 = xb[grow*3+1]; a2 = xb[grow*3+2];
        }
    }
    const float xx = fmaf(a0,a0, fmaf(a1,a1, a2*a2));
    unsigned short xh0=f2bf(a0), xh1=f2bf(a1), xh2=f2bf(a2);
    unsigned short nxh0=f2bf(-2.f*bf2f(xh0)), nxh1=f2bf(-2.f*bf2f(xh1)), nxh2=f2bf(-2.f*bf2f(xh2));
    unsigned short nxl0=f2bf(-2.f*(a0-bf2f(xh0))), nxl1=f2bf(-2.f*(a1-bf2f(xh1))),
                   nxl2=f2bf(-2.f*(a2-bf2f(xh2)));
    unsigned short xxh=f2bf(xx), xxl=f2bf(xx-bf2f(xxh));
    const short ONE = (short)0x3F80;
    bf16x8 A;
    if (h == 0){   // k0-7
        A[0]=(short)nxh0; A[1]=(short)nxh1; A[2]=(short)nxh2;
        A[3]=(short)nxl0; A[4]=(short)nxl1; A[5]=(short)nxl2;
        A[6]=(short)nxh0; A[7]=(short)nxh1;
    } else {       // k8-15
        A[0]=(short)nxh2; A[1]=(short)xxh; A[2]=(short)xxl;
        A[3]=ONE; A[4]=ONE; A[5]=0; A[6]=0; A[7]=0;
    }

    f32x16 zacc;
#pragma unroll
    for (int r = 0; r < 16; ++r) zacc[r] = 0.f;
    float rm[16];
#pragma unroll
    for (int r = 0; r < 16; ++r) rm[r] = BIGF;

    const uint4* __restrict__ bfp = bfrag + (size_t)c * NT * 64 + l;

    int t = t0;
    for (; t + 1 < t1; t += 2){
        const bf16x8 B1 = __builtin_bit_cast(bf16x8, bfp[(size_t)t * 64]);
        const bf16x8 B2 = __builtin_bit_cast(bf16x8, bfp[(size_t)(t + 1) * 64]);
        const f32x16 au1 = __builtin_amdgcn_mfma_f32_32x32x16_bf16(A, B1, zacc, 0, 0, 0);
        const f32x16 au2 = __builtin_amdgcn_mfma_f32_32x32x16_bf16(A, B2, zacc, 0, 0, 0);
#pragma unroll
        for (int r = 0; r < 16; ++r)
            rm[r] = fminf(fminf(rm[r], au1[r]), au2[r]);     // -> v_min3_f32
    }
    if (t < t1){
        const bf16x8 B1 = __builtin_bit_cast(bf16x8, bfp[(size_t)t * 64]);
        const f32x16 au1 = __builtin_amdgcn_mfma_f32_32x32x16_bf16(A, B1, zacc, 0, 0, 0);
#pragma unroll
        for (int r = 0; r < 16; ++r)
            rm[r] = fminf(rm[r], au1[r]);
    }

    // row-min butterfly within each 32-lane half (cols live across lanes)
#pragma unroll
    for (int r = 0; r < 16; ++r){
        float v = rm[r];
        v = fminf(v, __shfl_xor(v, 1, 64));
        v = fminf(v, __shfl_xor(v, 2, 64));
        v = fminf(v, __shfl_xor(v, 4, 64));
        v = fminf(v, __shfl_xor(v, 8, 64));
        v = fminf(v, __shfl_xor(v, 16, 64));
        rm[r] = v;
    }
    float* __restrict__ rp = rowpart + (size_t)(c * 4 + blockIdx.y) * RSTRIDE;
#pragma unroll
    for (int r = 0; r < 16; ++r){             // static index only (no scratch)
        if ((l & 31) == r){
            const int rowl = (r & 3) + 8 * (r >> 2) + 4 * h;
            const int gr = blockIdx.x * 128 + w * 32 + rowl;
            if (gr < Np) rp[gr] = rm[r];
        }
    }
}

// edge loss + normal consistency + laplacian cot scatter, one dispatch.
__global__ void mesh_k(const float* __restrict__ pred,
                       const int* __restrict__ edges, int E,
                       const int* __restrict__ pairs, int P,
                       const int* __restrict__ faces, int F,
                       int N, int B, float scaleE, float scaleP,
                       float* __restrict__ Lx, float* __restrict__ rowsum,
                       float* __restrict__ accum)
{
    const int tE = B * E, tP = B * P, tF = B * F;
    const int total = tE + tP + tF;
    float se = 0.f, sp = 0.f;
    for (int idx = blockIdx.x * blockDim.x + threadIdx.x; idx < total;
         idx += gridDim.x * blockDim.x) {
        if (idx < tE) {
            const int b = idx / E;
            const int e = idx - b * E;
            const float* __restrict__ vb = pred + (size_t)b * N * 3;
            const int i0 = edges[e * 2 + 0], i1 = edges[e * 2 + 1];
            float dx = vb[i0 * 3 + 0] - vb[i1 * 3 + 0];
            float dy = vb[i0 * 3 + 1] - vb[i1 * 3 + 1];
            float dz = vb[i0 * 3 + 2] - vb[i1 * 3 + 2];
            se += fmaf(dx, dx, fmaf(dy, dy, dz * dz));
        } else if (idx < tE + tP) {
            const int q = idx - tE;
            const int b = q / P;
            const int p = q - b * P;
            const float* __restrict__ vb = pred + (size_t)b * N * 3;
            const int a0 = pairs[p * 4 + 0], a1 = pairs[p * 4 + 1];
            const int a2 = pairs[p * 4 + 2], a3 = pairs[p * 4 + 3];
            float p0x = vb[a0 * 3], p0y = vb[a0 * 3 + 1], p0z = vb[a0 * 3 + 2];
            float ex = vb[a1 * 3] - p0x, ey = vb[a1 * 3 + 1] - p0y, ez = vb[a1 * 3 + 2] - p0z;
            float ux = vb[a2 * 3] - p0x, uy = vb[a2 * 3 + 1] - p0y, uz = vb[a2 * 3 + 2] - p0z;
            float wx = vb[a3 * 3] - p0x, wy = vb[a3 * 3 + 1] - p0y, wz = vb[a3 * 3 + 2] - p0z;
            float n0x = ey * uz - ez * uy;
            float n0y = ez * ux - ex * uz;
            float n0z = ex * uy - ey * ux;
            float n1x = -(ey * wz - ez * wy);
            float n1y = -(ez * wx - ex * wz);
            float n1z = -(ex * wy - ey * wx);
            float dt = n0x * n1x + n0y * n1y + n0z * n1z;
            float l0 = sqrtf(n0x * n0x + n0y * n0y + n0z * n0z);
            float l1 = sqrtf(n1x * n1x + n1y * n1y + n1z * n1z);
            sp += 1.0f - dt / (fmaxf(l0, 1e-8f) * fmaxf(l1, 1e-8f));
        } else {
            const int q = idx - tE - tP;
            const int b = q / F;
            const int f = q - b * F;
            const float* __restrict__ vb = pred + (size_t)b * N * 3;
            const int i0 = faces[f * 3 + 0], i1 = faces[f * 3 + 1], i2 = faces[f * 3 + 2];
            float v0x = vb[i0 * 3], v0y = vb[i0 * 3 + 1], v0z = vb[i0 * 3 + 2];
            float v1x = vb[i1 * 3], v1y = vb[i1 * 3 + 1], v1z = vb[i1 * 3 + 2];
            float v2x = vb[i2 * 3], v2y = vb[i2 * 3 + 1], v2z = vb[i2 * 3 + 2];
            float ax = v1x - v2x, ay = v1y - v2y, az = v1z - v2z;
            float bx = v0x - v2x, by = v0y - v2y, bz = v0z - v2z;
            float cx = v0x - v1x, cy = v0y - v1y, cz = v0z - v1z;
            float A  = sqrtf(ax * ax + ay * ay + az * az);
            float Bl = sqrtf(bx * bx + by * by + bz * bz);
            float C  = sqrtf(cx * cx + cy * cy + cz * cz);
            float s2 = 0.5f * (A + Bl + C);
            float area = sqrtf(fmaxf(s2 * (s2 - A) * (s2 - Bl) * (s2 - C), 1e-12f));
            float A2 = A * A, B2 = Bl * Bl, C2 = C * C;
            float inv4a = 1.0f / (4.0f * area);
            float cota = (B2 + C2 - A2) * inv4a;
            float cotb = (A2 + C2 - B2) * inv4a;
            float cotc = (A2 + B2 - C2) * inv4a;

            float* __restrict__ Lb = Lx + (size_t)b * N * 3;
            float* __restrict__ rb = rowsum + (size_t)b * N;
            #define SCAT(i, j, wv)                                            \
                atomicAdd(&Lb[(i) * 3 + 0], (wv) * vb[(j) * 3 + 0]);          \
                atomicAdd(&Lb[(i) * 3 + 1], (wv) * vb[(j) * 3 + 1]);          \
                atomicAdd(&Lb[(i) * 3 + 2], (wv) * vb[(j) * 3 + 2]);          \
                atomicAdd(&rb[(i)], (wv));
            SCAT(i1, i2, cota) SCAT(i2, i1, cota)
            SCAT(i2, i0, cotb) SCAT(i0, i2, cotb)
            SCAT(i0, i1, cotc) SCAT(i1, i0, cotc)
            #undef SCAT
        }
    }
    se = wave_sum(se);
    sp = wave_sum(sp);
    if ((threadIdx.x & 63) == 0) atomicAdd(accum, fmaf(se, scaleE, sp * scaleP));
}

// rowpart 4-chunk min + clamp + lap residual, one dispatch.
__global__ void finalize_k(const float* __restrict__ rowpart,
                           const float* __restrict__ pred, const float* __restrict__ Lx,
                           const float* __restrict__ rowsum,
                           int N, float sMain, float sVel, float scaleL,
                           float* __restrict__ accum)
{
    const int total = 8 * N + 2 * N;
    float sm = 0.f, sv = 0.f, sl = 0.f;
    for (int idx = blockIdx.x * blockDim.x + threadIdx.x; idx < total;
         idx += gridDim.x * blockDim.x) {
        if (idx < 8 * N) {
            const int c = idx / N, i = idx - c * N;
            const int ds = (c >> 1) & 1;
            if (i < N - ds) {
                const float* rp = rowpart + (size_t)c * 4 * RSTRIDE;
                float v = fminf(fminf(rp[i], rp[RSTRIDE + i]),
                                fminf(rp[2*RSTRIDE + i], rp[3*RSTRIDE + i]));
                float d = fmaxf(v, 0.f);
                if (ds) sv += d; else sm += d;
            }
        } else {
            const int q = idx - 8 * N;       // B*N lap entries
            float rs = rowsum[q];
            float nw = rs > 0.f ? 1.0f / rs : 0.f;
            float rx = Lx[q*3+0]*nw - pred[q*3+0];
            float ry = Lx[q*3+1]*nw - pred[q*3+1];
            float rz = Lx[q*3+2]*nw - pred[q*3+2];
            sl += sqrtf(rx*rx + ry*ry + rz*rz);
        }
    }
    sm = wave_sum(sm); sv = wave_sum(sv); sl = wave_sum(sl);
    if ((threadIdx.x & 63) == 0)
        atomicAdd(accum, fmaf(sm, sMain, fmaf(sv, sVel, sl * scaleL)));
}

__global__ void write_out_k(const float* __restrict__ accum, float* __restrict__ out)
{
    out[0] = accum[0];
}

extern "C" void kernel_launch(void* const* d_in, const int* in_sizes, int n_in,
                              void* d_out, int out_size, void* d_ws, size_t ws_size,
                              hipStream_t stream)
{
    const float* pred = (const float*)d_in[0];
    const float* tgt  = (const float*)d_in[1];
    const int* faces  = (const int*)d_in[2];
    const int* edges  = (const int*)d_in[3];
    const int* pairs  = (const int*)d_in[4];

    const int B = 2;
    const int N = in_sizes[0] / (3 * B);   // 8281
    const int F = in_sizes[2] / 3;
    const int E = in_sizes[3] / 2;
    const int P = in_sizes[4] / 4;
    const int NT = (N + 31) >> 5;          // 259

    // workspace layout (4B units):
    // [accum 8][Lx B*N*3][rowsum B*N][rowpart 8*4*RSTRIDE][bfrag 8*NT*64 u4]
    float* ws      = (float*)d_ws;
    float* accum   = ws;
    float* Lx      = ws + 8;
    float* rowsum  = Lx + (size_t)B * N * 3;
    float* rowpart = rowsum + (size_t)B * N;
    size_t off     = 8 + (size_t)B*N*3 + (size_t)B*N + (size_t)32*RSTRIDE;
    uint4* bfrag   = (uint4*)(ws + off);   // off*4 16B-aligned (off div by 4)

    const int nzero = 8 + B * N * 3 + B * N;

    init_ws_k<<<64, dim3(256), 0, stream>>>(ws, nzero);

    bprep_k<<<dim3((8 * NT + 3) / 4), dim3(256), 0, stream>>>(pred, tgt, N, bfrag);

    chamfer_mfma_k<<<dim3((N + 127) / 128, 4, 8), dim3(256), 0, stream>>>(
        pred, tgt, N, bfrag, rowpart);

    mesh_k<<<128, dim3(256), 0, stream>>>(pred, edges, E, pairs, P, faces, F, N, B,
                                          W_EDGE / ((float)B * (float)E),
                                          W_NORMAL / ((float)B * (float)P),
                                          Lx, rowsum, accum);

    finalize_k<<<96, dim3(256), 0, stream>>>(rowpart, pred, Lx, rowsum, N,
                                             1.0f / ((float)B * (float)N),
                                             W_VEL / ((float)B * (float)(N - 1)),
                                             W_LAP / ((float)B * (float)N), accum);

    write_out_k<<<1, 1, 0, stream>>>(accum, (float*)d_out);
}

// Round 9
// 77.224 us; speedup vs baseline: 1.3249x; 1.2756x over previous
//
#include <hip/hip_runtime.h>

// ---------------------------------------------------------------------------
// Chamfer_Loss: chamfer(pred,tgt) + W_EDGE*edge + W_LAP*cotLap + W_NORMAL*nc
//               + W_VEL*chamfer(diff(pred), diff(tgt))
// B=2, N=8281 (g=91), fp32 in/out. Output: 1 scalar.
// R9: 8-deep B-fragment load batching in the MFMA chamfer sweep. R8 decomposed
//     to MFMA 6.7us + VALU 28us + ~40us vmcnt stall (2 loads in flight,
//     ~250cyc L2 latency, no cross-iteration pipelining by the compiler).
//     Static names T0..T7, loads issued up-front, then 4 MFMA-pairs + min3.
// ---------------------------------------------------------------------------

typedef unsigned int uint32;
typedef __attribute__((ext_vector_type(8)))  short bf16x8;
typedef __attribute__((ext_vector_type(16))) float f32x16;

#define W_EDGE   0.5f
#define W_LAP    0.05f
#define W_NORMAL 0.01f
#define W_VEL    10.0f
#define BIGF     3.0e38f
#define RSTRIDE  8320      // padded row stride (>= 8281, 8320 = 65*128)

__device__ __forceinline__ unsigned short f2bf(float f){
    uint32 b = __float_as_uint(f);
    b += 0x7FFFu + ((b >> 16) & 1u);          // RNE
    return (unsigned short)(b >> 16);
}
__device__ __forceinline__ float bf2f(unsigned short h){
    return __uint_as_float(((uint32)h) << 16);
}

__device__ __forceinline__ float wave_sum(float v) {
#pragma unroll
    for (int o = 32; o > 0; o >>= 1) v += __shfl_down(v, o, 64);
    return v;
}

// Zero [accum | Lx | rowsum].
__global__ void init_ws_k(float* __restrict__ ws, int nzero)
{
    uint32* w = (uint32*)ws;
    for (int i = blockIdx.x * blockDim.x + threadIdx.x; i < nzero;
         i += gridDim.x * blockDim.x)
        w[i] = 0u;
}

// ---------------------------------------------------------------------------
// B-fragment prep: one wave per (combo, y-tile).
// combo c = dir*4 + ds*2 + b; dir 0: y-side = tgt, dir 1: y-side = pred;
// ds: 0 main, 1 velocity-diff; b: batch.
// K-slot map (A-side in chamfer kernel):
//  k0-2: A=-2xh B=yh | k3-5: A=-2xl B=yh | k6-8: A=-2xh B=yl
//  k9:   A=xxh  B=1  | k10:  A=xxl B=1  | k11: A=1 B=yyh | k12: A=1 B=yyl
//  k13-15: 0.   acc = xx + yy - 2 x.y = d  (pad col: yy=BIG => never min)
// Lane l: col = l&31, holds k = (l>>5)*8 + i.
// ---------------------------------------------------------------------------
__global__ void bprep_k(const float* __restrict__ pred, const float* __restrict__ tgt,
                        int N, uint4* __restrict__ bfrag)
{
    const int NT = (N + 31) >> 5;
    const int gt = blockIdx.x * 4 + (threadIdx.x >> 6);
    if (gt >= 8 * NT) return;
    const int c = gt / NT, t = gt - c * NT;
    const int dir = c >> 2, ds = (c >> 1) & 1, b = c & 1;
    const int Np = N - ds;
    const int l = threadIdx.x & 63;
    const int col = t * 32 + (l & 31);
    const float* __restrict__ yb = (dir ? pred : tgt) + (size_t)b * N * 3;
    float y0 = 0.f, y1 = 0.f, y2 = 0.f;
    const bool valid = col < Np;
    if (valid){
        if (ds){
            y0 = yb[(col+1)*3+0] - yb[col*3+0];
            y1 = yb[(col+1)*3+1] - yb[col*3+1];
            y2 = yb[(col+1)*3+2] - yb[col*3+2];
        } else {
            y0 = yb[col*3+0]; y1 = yb[col*3+1]; y2 = yb[col*3+2];
        }
    }
    const float yy = fmaf(y0,y0, fmaf(y1,y1, y2*y2));
    unsigned short yh0=f2bf(y0), yh1=f2bf(y1), yh2=f2bf(y2);
    unsigned short yl0=f2bf(y0-bf2f(yh0)), yl1=f2bf(y1-bf2f(yh1)), yl2=f2bf(y2-bf2f(yh2));
    unsigned short yyh, yyl;
    if (valid){ yyh = f2bf(yy); yyl = f2bf(yy - bf2f(yyh)); }
    else      { yyh = f2bf(BIGF); yyl = 0; }
    const short ONE = (short)0x3F80;
    bf16x8 Bu;
    if (l < 32){        // k0-7
        Bu[0]=(short)yh0; Bu[1]=(short)yh1; Bu[2]=(short)yh2;
        Bu[3]=(short)yh0; Bu[4]=(short)yh1; Bu[5]=(short)yh2;
        Bu[6]=(short)yl0; Bu[7]=(short)yl1;
    } else {            // k8-15
        Bu[0]=(short)yl2; Bu[1]=ONE; Bu[2]=ONE; Bu[3]=(short)yyh; Bu[4]=(short)yyl;
        Bu[5]=0; Bu[6]=0; Bu[7]=0;
    }
    bfrag[(size_t)(c * NT + t) * 64 + l] = __builtin_bit_cast(uint4, Bu);
}

// ---------------------------------------------------------------------------
// MFMA chamfer, row-min only. grid (65 x-blocks, 4 y-chunks, 8 combos),
// 256 thr = 4 waves; wave w owns rows bx*128 + w*32..+31, sweeps its chunk's
// tiles in batches of 8 (8 loads in flight -> latency amortized 8x).
// rowpart[c][chunk][row] = min_{cols in chunk} d(row, col)
// ---------------------------------------------------------------------------
__global__ __launch_bounds__(256)
void chamfer_mfma_k(const float* __restrict__ pred, const float* __restrict__ tgt,
                    int N, const uint4* __restrict__ bfrag,
                    float* __restrict__ rowpart)
{
    const int c = blockIdx.z;
    const int dir = c >> 2, ds = (c >> 1) & 1, b = c & 1;
    const int Np = N - ds;
    const int NT = (N + 31) >> 5;            // 259
    const int TC = (NT + 3) >> 2;            // 65
    const int t0 = blockIdx.y * TC;
    const int t1 = min(NT, t0 + TC);
    const int w = threadIdx.x >> 6, l = threadIdx.x & 63;
    const int h = l >> 5;
    const int grow = blockIdx.x * 128 + w * 32 + (l & 31);

    const float* __restrict__ xb = (dir ? tgt : pred) + (size_t)b * N * 3;
    float a0 = 0.f, a1 = 0.f, a2 = 0.f;
    const bool xvalid = grow < Np;
    if (xvalid){
        if (ds){
            a0 = xb[(grow+1)*3+0] - xb[grow*3+0];
            a1 = xb[(grow+1)*3+1] - xb[grow*3+1];
            a2 = xb[(grow+1)*3+2] - xb[grow*3+2];
        } else {
            a0 = xb[grow*3+0]; a1 = xb[grow*3+1]; a2 = xb[grow*3+2];
        }
    }
    const float xx = fmaf(a0,a0, fmaf(a1,a1, a2*a2));
    unsigned short xh0=f2bf(a0), xh1=f2bf(a1), xh2=f2bf(a2);
    unsigned short nxh0=f2bf(-2.f*bf2f(xh0)), nxh1=f2bf(-2.f*bf2f(xh1)), nxh2=f2bf(-2.f*bf2f(xh2));
    unsigned short nxl0=f2bf(-2.f*(a0-bf2f(xh0))), nxl1=f2bf(-2.f*(a1-bf2f(xh1))),
                   nxl2=f2bf(-2.f*(a2-bf2f(xh2)));
    unsigned short xxh=f2bf(xx), xxl=f2bf(xx-bf2f(xxh));
    const short ONE = (short)0x3F80;
    bf16x8 A;
    if (h == 0){   // k0-7
        A[0]=(short)nxh0; A[1]=(short)nxh1; A[2]=(short)nxh2;
        A[3]=(short)nxl0; A[4]=(short)nxl1; A[5]=(short)nxl2;
        A[6]=(short)nxh0; A[7]=(short)nxh1;
    } else {       // k8-15
        A[0]=(short)nxh2; A[1]=(short)xxh; A[2]=(short)xxl;
        A[3]=ONE; A[4]=ONE; A[5]=0; A[6]=0; A[7]=0;
    }

    f32x16 zacc;
#pragma unroll
    for (int r = 0; r < 16; ++r) zacc[r] = 0.f;
    float rm[16];
#pragma unroll
    for (int r = 0; r < 16; ++r) rm[r] = BIGF;

    const uint4* __restrict__ bfp = bfrag + (size_t)c * NT * 64 + l;

    int t = t0;
    for (; t + 8 <= t1; t += 8){
        // issue all 8 tile loads up-front (independent, stay in flight)
        const bf16x8 T0 = __builtin_bit_cast(bf16x8, bfp[(size_t)(t+0) * 64]);
        const bf16x8 T1 = __builtin_bit_cast(bf16x8, bfp[(size_t)(t+1) * 64]);
        const bf16x8 T2 = __builtin_bit_cast(bf16x8, bfp[(size_t)(t+2) * 64]);
        const bf16x8 T3 = __builtin_bit_cast(bf16x8, bfp[(size_t)(t+3) * 64]);
        const bf16x8 T4 = __builtin_bit_cast(bf16x8, bfp[(size_t)(t+4) * 64]);
        const bf16x8 T5 = __builtin_bit_cast(bf16x8, bfp[(size_t)(t+5) * 64]);
        const bf16x8 T6 = __builtin_bit_cast(bf16x8, bfp[(size_t)(t+6) * 64]);
        const bf16x8 T7 = __builtin_bit_cast(bf16x8, bfp[(size_t)(t+7) * 64]);

        const f32x16 u0 = __builtin_amdgcn_mfma_f32_32x32x16_bf16(A, T0, zacc, 0, 0, 0);
        const f32x16 u1 = __builtin_amdgcn_mfma_f32_32x32x16_bf16(A, T1, zacc, 0, 0, 0);
#pragma unroll
        for (int r = 0; r < 16; ++r) rm[r] = fminf(fminf(rm[r], u0[r]), u1[r]);
        const f32x16 u2 = __builtin_amdgcn_mfma_f32_32x32x16_bf16(A, T2, zacc, 0, 0, 0);
        const f32x16 u3 = __builtin_amdgcn_mfma_f32_32x32x16_bf16(A, T3, zacc, 0, 0, 0);
#pragma unroll
        for (int r = 0; r < 16; ++r) rm[r] = fminf(fminf(rm[r], u2[r]), u3[r]);
        const f32x16 u4 = __builtin_amdgcn_mfma_f32_32x32x16_bf16(A, T4, zacc, 0, 0, 0);
        const f32x16 u5 = __builtin_amdgcn_mfma_f32_32x32x16_bf16(A, T5, zacc, 0, 0, 0);
#pragma unroll
        for (int r = 0; r < 16; ++r) rm[r] = fminf(fminf(rm[r], u4[r]), u5[r]);
        const f32x16 u6 = __builtin_amdgcn_mfma_f32_32x32x16_bf16(A, T6, zacc, 0, 0, 0);
        const f32x16 u7 = __builtin_amdgcn_mfma_f32_32x32x16_bf16(A, T7, zacc, 0, 0, 0);
#pragma unroll
        for (int r = 0; r < 16; ++r) rm[r] = fminf(fminf(rm[r], u6[r]), u7[r]);
    }
    for (; t < t1; ++t){
        const bf16x8 T0 = __builtin_bit_cast(bf16x8, bfp[(size_t)t * 64]);
        const f32x16 u0 = __builtin_amdgcn_mfma_f32_32x32x16_bf16(A, T0, zacc, 0, 0, 0);
#pragma unroll
        for (int r = 0; r < 16; ++r) rm[r] = fminf(rm[r], u0[r]);
    }

    // row-min butterfly within each 32-lane half (cols live across lanes)
#pragma unroll
    for (int r = 0; r < 16; ++r){
        float v = rm[r];
        v = fminf(v, __shfl_xor(v, 1, 64));
        v = fminf(v, __shfl_xor(v, 2, 64));
        v = fminf(v, __shfl_xor(v, 4, 64));
        v = fminf(v, __shfl_xor(v, 8, 64));
        v = fminf(v, __shfl_xor(v, 16, 64));
        rm[r] = v;
    }
    float* __restrict__ rp = rowpart + (size_t)(c * 4 + blockIdx.y) * RSTRIDE;
#pragma unroll
    for (int r = 0; r < 16; ++r){             // static index only (no scratch)
        if ((l & 31) == r){
            const int rowl = (r & 3) + 8 * (r >> 2) + 4 * h;
            const int gr = blockIdx.x * 128 + w * 32 + rowl;
            if (gr < Np) rp[gr] = rm[r];
        }
    }
}

// edge loss + normal consistency + laplacian cot scatter, one dispatch.
__global__ void mesh_k(const float* __restrict__ pred,
                       const int* __restrict__ edges, int E,
                       const int* __restrict__ pairs, int P,
                       const int* __restrict__ faces, int F,
                       int N, int B, float scaleE, float scaleP,
                       float* __restrict__ Lx, float* __restrict__ rowsum,
                       float* __restrict__ accum)
{
    const int tE = B * E, tP = B * P, tF = B * F;
    const int total = tE + tP + tF;
    float se = 0.f, sp = 0.f;
    for (int idx = blockIdx.x * blockDim.x + threadIdx.x; idx < total;
         idx += gridDim.x * blockDim.x) {
        if (idx < tE) {
            const int b = idx / E;
            const int e = idx - b * E;
            const float* __restrict__ vb = pred + (size_t)b * N * 3;
            const int i0 = edges[e * 2 + 0], i1 = edges[e * 2 + 1];
            float dx = vb[i0 * 3 + 0] - vb[i1 * 3 + 0];
            float dy = vb[i0 * 3 + 1] - vb[i1 * 3 + 1];
            float dz = vb[i0 * 3 + 2] - vb[i1 * 3 + 2];
            se += fmaf(dx, dx, fmaf(dy, dy, dz * dz));
        } else if (idx < tE + tP) {
            const int q = idx - tE;
            const int b = q / P;
            const int p = q - b * P;
            const float* __restrict__ vb = pred + (size_t)b * N * 3;
            const int a0 = pairs[p * 4 + 0], a1 = pairs[p * 4 + 1];
            const int a2 = pairs[p * 4 + 2], a3 = pairs[p * 4 + 3];
            float p0x = vb[a0 * 3], p0y = vb[a0 * 3 + 1], p0z = vb[a0 * 3 + 2];
            float ex = vb[a1 * 3] - p0x, ey = vb[a1 * 3 + 1] - p0y, ez = vb[a1 * 3 + 2] - p0z;
            float ux = vb[a2 * 3] - p0x, uy = vb[a2 * 3 + 1] - p0y, uz = vb[a2 * 3 + 2] - p0z;
            float wx = vb[a3 * 3] - p0x, wy = vb[a3 * 3 + 1] - p0y, wz = vb[a3 * 3 + 2] - p0z;
            float n0x = ey * uz - ez * uy;
            float n0y = ez * ux - ex * uz;
            float n0z = ex * uy - ey * ux;
            float n1x = -(ey * wz - ez * wy);
            float n1y = -(ez * wx - ex * wz);
            float n1z = -(ex * wy - ey * wx);
            float dt = n0x * n1x + n0y * n1y + n0z * n1z;
            float l0 = sqrtf(n0x * n0x + n0y * n0y + n0z * n0z);
            float l1 = sqrtf(n1x * n1x + n1y * n1y + n1z * n1z);
            sp += 1.0f - dt / (fmaxf(l0, 1e-8f) * fmaxf(l1, 1e-8f));
        } else {
            const int q = idx - tE - tP;
            const int b = q / F;
            const int f = q - b * F;
            const float* __restrict__ vb = pred + (size_t)b * N * 3;
            const int i0 = faces[f * 3 + 0], i1 = faces[f * 3 + 1], i2 = faces[f * 3 + 2];
            float v0x = vb[i0 * 3], v0y = vb[i0 * 3 + 1], v0z = vb[i0 * 3 + 2];
            float v1x = vb[i1 * 3], v1y = vb[i1 * 3 + 1], v1z = vb[i1 * 3 + 2];
            float v2x = vb[i2 * 3], v2y = vb[i2 * 3 + 1], v2z = vb[i2 * 3 + 2];
            float ax = v1x - v2x, ay = v1y - v2y, az = v1z - v2z;
            float bx = v0x - v2x, by = v0y - v2y, bz = v0z - v2z;
            float cx = v0x - v1x, cy = v0y - v1y, cz = v0z - v1z;
            float A  = sqrtf(ax * ax + ay * ay + az * az);
            float Bl = sqrtf(bx * bx + by * by + bz * bz);
            float C  = sqrtf(cx * cx + cy * cy + cz * cz);
            float s2 = 0.5f * (A + Bl + C);
            float area = sqrtf(fmaxf(s2 * (s2 - A) * (s2 - Bl) * (s2 - C), 1e-12f));
            float A2 = A * A, B2 = Bl * Bl, C2 = C * C;
            float inv4a = 1.0f / (4.0f * area);
            float cota = (B2 + C2 - A2) * inv4a;
            float cotb = (A2 + C2 - B2) * inv4a;
            float cotc = (A2 + B2 - C2) * inv4a;

            float* __restrict__ Lb = Lx + (size_t)b * N * 3;
            float* __restrict__ rb = rowsum + (size_t)b * N;
            #define SCAT(i, j, wv)                                            \
                atomicAdd(&Lb[(i) * 3 + 0], (wv) * vb[(j) * 3 + 0]);          \
                atomicAdd(&Lb[(i) * 3 + 1], (wv) * vb[(j) * 3 + 1]);          \
                atomicAdd(&Lb[(i) * 3 + 2], (wv) * vb[(j) * 3 + 2]);          \
                atomicAdd(&rb[(i)], (wv));
            SCAT(i1, i2, cota) SCAT(i2, i1, cota)
            SCAT(i2, i0, cotb) SCAT(i0, i2, cotb)
            SCAT(i0, i1, cotc) SCAT(i1, i0, cotc)
            #undef SCAT
        }
    }
    se = wave_sum(se);
    sp = wave_sum(sp);
    if ((threadIdx.x & 63) == 0) atomicAdd(accum, fmaf(se, scaleE, sp * scaleP));
}

// rowpart 4-chunk min + clamp + lap residual, one dispatch.
__global__ void finalize_k(const float* __restrict__ rowpart,
                           const float* __restrict__ pred, const float* __restrict__ Lx,
                           const float* __restrict__ rowsum,
                           int N, float sMain, float sVel, float scaleL,
                           float* __restrict__ accum)
{
    const int total = 8 * N + 2 * N;
    float sm = 0.f, sv = 0.f, sl = 0.f;
    for (int idx = blockIdx.x * blockDim.x + threadIdx.x; idx < total;
         idx += gridDim.x * blockDim.x) {
        if (idx < 8 * N) {
            const int c = idx / N, i = idx - c * N;
            const int ds = (c >> 1) & 1;
            if (i < N - ds) {
                const float* rp = rowpart + (size_t)c * 4 * RSTRIDE;
                float v = fminf(fminf(rp[i], rp[RSTRIDE + i]),
                                fminf(rp[2*RSTRIDE + i], rp[3*RSTRIDE + i]));
                float d = fmaxf(v, 0.f);
                if (ds) sv += d; else sm += d;
            }
        } else {
            const int q = idx - 8 * N;       // B*N lap entries
            float rs = rowsum[q];
            float nw = rs > 0.f ? 1.0f / rs : 0.f;
            float rx = Lx[q*3+0]*nw - pred[q*3+0];
            float ry = Lx[q*3+1]*nw - pred[q*3+1];
            float rz = Lx[q*3+2]*nw - pred[q*3+2];
            sl += sqrtf(rx*rx + ry*ry + rz*rz);
        }
    }
    sm = wave_sum(sm); sv = wave_sum(sv); sl = wave_sum(sl);
    if ((threadIdx.x & 63) == 0)
        atomicAdd(accum, fmaf(sm, sMain, fmaf(sv, sVel, sl * scaleL)));
}

__global__ void write_out_k(const float* __restrict__ accum, float* __restrict__ out)
{
    out[0] = accum[0];
}

extern "C" void kernel_launch(void* const* d_in, const int* in_sizes, int n_in,
                              void* d_out, int out_size, void* d_ws, size_t ws_size,
                              hipStream_t stream)
{
    const float* pred = (const float*)d_in[0];
    const float* tgt  = (const float*)d_in[1];
    const int* faces  = (const int*)d_in[2];
    const int* edges  = (const int*)d_in[3];
    const int* pairs  = (const int*)d_in[4];

    const int B = 2;
    const int N = in_sizes[0] / (3 * B);   // 8281
    const int F = in_sizes[2] / 3;
    const int E = in_sizes[3] / 2;
    const int P = in_sizes[4] / 4;
    const int NT = (N + 31) >> 5;          // 259

    // workspace layout (4B units):
    // [accum 8][Lx B*N*3][rowsum B*N][rowpart 8*4*RSTRIDE][bfrag 8*NT*64 u4]
    float* ws      = (float*)d_ws;
    float* accum   = ws;
    float* Lx      = ws + 8;
    float* rowsum  = Lx + (size_t)B * N * 3;
    float* rowpart = rowsum + (size_t)B * N;
    size_t off     = 8 + (size_t)B*N*3 + (size_t)B*N + (size_t)32*RSTRIDE;
    uint4* bfrag   = (uint4*)(ws + off);   // off*4 16B-aligned (off div by 4)

    const int nzero = 8 + B * N * 3 + B * N;

    init_ws_k<<<64, dim3(256), 0, stream>>>(ws, nzero);

    bprep_k<<<dim3((8 * NT + 3) / 4), dim3(256), 0, stream>>>(pred, tgt, N, bfrag);

    chamfer_mfma_k<<<dim3((N + 127) / 128, 4, 8), dim3(256), 0, stream>>>(
        pred, tgt, N, bfrag, rowpart);

    mesh_k<<<128, dim3(256), 0, stream>>>(pred, edges, E, pairs, P, faces, F, N, B,
                                          W_EDGE / ((float)B * (float)E),
                                          W_NORMAL / ((float)B * (float)P),
                                          Lx, rowsum, accum);

    finalize_k<<<96, dim3(256), 0, stream>>>(rowpart, pred, Lx, rowsum, N,
                                             1.0f / ((float)B * (float)N),
                                             W_VEL / ((float)B * (float)(N - 1)),
                                             W_LAP / ((float)B * (float)N), accum);

    write_out_k<<<1, 1, 0, stream>>>(accum, (float*)d_out);
}

// Round 10
// 71.509 us; speedup vs baseline: 1.4308x; 1.0799x over previous
//
#include <hip/hip_runtime.h>

// ---------------------------------------------------------------------------
// Chamfer_Loss: chamfer(pred,tgt) + W_EDGE*edge + W_LAP*cotLap + W_NORMAL*nc
//               + W_VEL*chamfer(diff(pred), diff(tgt))
// B=2, N=8281 (g=91), fp32 in/out. Output: 1 scalar.
// R10: occupancy fix for the MFMA chamfer. R9 sat at 3 waves/SIMD because the
//     8 batched accumulators lived in AGPRs (8x16=128 regs). Now:
//     __launch_bounds__(256,4) (128-reg budget) + pairwise MFMA->min with
//     sched_barrier(0) between pairs caps live accumulators at 2.
//     Also fused ws-zeroing into bprep_k (one fewer dispatch).
// ---------------------------------------------------------------------------

typedef unsigned int uint32;
typedef __attribute__((ext_vector_type(8)))  short bf16x8;
typedef __attribute__((ext_vector_type(16))) float f32x16;

#define W_EDGE   0.5f
#define W_LAP    0.05f
#define W_NORMAL 0.01f
#define W_VEL    10.0f
#define BIGF     3.0e38f
#define RSTRIDE  8320      // padded row stride (>= 8281, 8320 = 65*128)

__device__ __forceinline__ unsigned short f2bf(float f){
    uint32 b = __float_as_uint(f);
    b += 0x7FFFu + ((b >> 16) & 1u);          // RNE
    return (unsigned short)(b >> 16);
}
__device__ __forceinline__ float bf2f(unsigned short h){
    return __uint_as_float(((uint32)h) << 16);
}

__device__ __forceinline__ float wave_sum(float v) {
#pragma unroll
    for (int o = 32; o > 0; o >>= 1) v += __shfl_down(v, o, 64);
    return v;
}

// ---------------------------------------------------------------------------
// B-fragment prep + workspace zeroing (fused; disjoint memory, same dispatch).
// combo c = dir*4 + ds*2 + b; dir 0: y-side = tgt, dir 1: y-side = pred;
// ds: 0 main, 1 velocity-diff; b: batch.
// K-slot map (A-side in chamfer kernel):
//  k0-2: A=-2xh B=yh | k3-5: A=-2xl B=yh | k6-8: A=-2xh B=yl
//  k9:   A=xxh  B=1  | k10:  A=xxl B=1  | k11: A=1 B=yyh | k12: A=1 B=yyl
//  k13-15: 0.   acc = xx + yy - 2 x.y = d  (pad col: yy=BIG => never min)
// Lane l: col = l&31, holds k = (l>>5)*8 + i.
// ---------------------------------------------------------------------------
__global__ void bprep_k(const float* __restrict__ pred, const float* __restrict__ tgt,
                        int N, uint4* __restrict__ bfrag,
                        float* __restrict__ ws, int nzero)
{
    // grid-stride zero of [accum | Lx | rowsum]
    {
        uint32* w = (uint32*)ws;
        for (int i = blockIdx.x * blockDim.x + threadIdx.x; i < nzero;
             i += gridDim.x * blockDim.x)
            w[i] = 0u;
    }

    const int NT = (N + 31) >> 5;
    const int gt = blockIdx.x * 4 + (threadIdx.x >> 6);
    if (gt >= 8 * NT) return;
    const int c = gt / NT, t = gt - c * NT;
    const int dir = c >> 2, ds = (c >> 1) & 1, b = c & 1;
    const int Np = N - ds;
    const int l = threadIdx.x & 63;
    const int col = t * 32 + (l & 31);
    const float* __restrict__ yb = (dir ? pred : tgt) + (size_t)b * N * 3;
    float y0 = 0.f, y1 = 0.f, y2 = 0.f;
    const bool valid = col < Np;
    if (valid){
        if (ds){
            y0 = yb[(col+1)*3+0] - yb[col*3+0];
            y1 = yb[(col+1)*3+1] - yb[col*3+1];
            y2 = yb[(col+1)*3+2] - yb[col*3+2];
        } else {
            y0 = yb[col*3+0]; y1 = yb[col*3+1]; y2 = yb[col*3+2];
        }
    }
    const float yy = fmaf(y0,y0, fmaf(y1,y1, y2*y2));
    unsigned short yh0=f2bf(y0), yh1=f2bf(y1), yh2=f2bf(y2);
    unsigned short yl0=f2bf(y0-bf2f(yh0)), yl1=f2bf(y1-bf2f(yh1)), yl2=f2bf(y2-bf2f(yh2));
    unsigned short yyh, yyl;
    if (valid){ yyh = f2bf(yy); yyl = f2bf(yy - bf2f(yyh)); }
    else      { yyh = f2bf(BIGF); yyl = 0; }
    const short ONE = (short)0x3F80;
    bf16x8 Bu;
    if (l < 32){        // k0-7
        Bu[0]=(short)yh0; Bu[1]=(short)yh1; Bu[2]=(short)yh2;
        Bu[3]=(short)yh0; Bu[4]=(short)yh1; Bu[5]=(short)yh2;
        Bu[6]=(short)yl0; Bu[7]=(short)yl1;
    } else {            // k8-15
        Bu[0]=(short)yl2; Bu[1]=ONE; Bu[2]=ONE; Bu[3]=(short)yyh; Bu[4]=(short)yyl;
        Bu[5]=0; Bu[6]=0; Bu[7]=0;
    }
    bfrag[(size_t)(c * NT + t) * 64 + l] = __builtin_bit_cast(uint4, Bu);
}

// ---------------------------------------------------------------------------
// MFMA chamfer, row-min only. grid (65 x-blocks, 4 y-chunks, 8 combos),
// 256 thr = 4 waves; wave w owns rows bx*128 + w*32..+31, sweeps its chunk's
// tiles in batches of 8 loads; compute as 4 pairs {2 MFMA -> 16 min3} with
// sched_barrier(0) between pairs (<=2 live accumulators -> fits 128-reg
// budget of launch_bounds(256,4) -> 4 waves/SIMD).
// rowpart[c][chunk][row] = min_{cols in chunk} d(row, col)
// ---------------------------------------------------------------------------
__global__ __launch_bounds__(256, 4)
void chamfer_mfma_k(const float* __restrict__ pred, const float* __restrict__ tgt,
                    int N, const uint4* __restrict__ bfrag,
                    float* __restrict__ rowpart)
{
    const int c = blockIdx.z;
    const int dir = c >> 2, ds = (c >> 1) & 1, b = c & 1;
    const int Np = N - ds;
    const int NT = (N + 31) >> 5;            // 259
    const int TC = (NT + 3) >> 2;            // 65
    const int t0 = blockIdx.y * TC;
    const int t1 = min(NT, t0 + TC);
    const int w = threadIdx.x >> 6, l = threadIdx.x & 63;
    const int h = l >> 5;
    const int grow = blockIdx.x * 128 + w * 32 + (l & 31);

    const float* __restrict__ xb = (dir ? tgt : pred) + (size_t)b * N * 3;
    float a0 = 0.f, a1 = 0.f, a2 = 0.f;
    const bool xvalid = grow < Np;
    if (xvalid){
        if (ds){
            a0 = xb[(grow+1)*3+0] - xb[grow*3+0];
            a1 = xb[(grow+1)*3+1] - xb[grow*3+1];
            a2 = xb[(grow+1)*3+2] - xb[grow*3+2];
        } else {
            a0 = xb[grow*3+0]; a1 = xb[grow*3+1]; a2 = xb[grow*3+2];
        }
    }
    const float xx = fmaf(a0,a0, fmaf(a1,a1, a2*a2));
    unsigned short xh0=f2bf(a0), xh1=f2bf(a1), xh2=f2bf(a2);
    unsigned short nxh0=f2bf(-2.f*bf2f(xh0)), nxh1=f2bf(-2.f*bf2f(xh1)), nxh2=f2bf(-2.f*bf2f(xh2));
    unsigned short nxl0=f2bf(-2.f*(a0-bf2f(xh0))), nxl1=f2bf(-2.f*(a1-bf2f(xh1))),
                   nxl2=f2bf(-2.f*(a2-bf2f(xh2)));
    unsigned short xxh=f2bf(xx), xxl=f2bf(xx-bf2f(xxh));
    const short ONE = (short)0x3F80;
    bf16x8 A;
    if (h == 0){   // k0-7
        A[0]=(short)nxh0; A[1]=(short)nxh1; A[2]=(short)nxh2;
        A[3]=(short)nxl0; A[4]=(short)nxl1; A[5]=(short)nxl2;
        A[6]=(short)nxh0; A[7]=(short)nxh1;
    } else {       // k8-15
        A[0]=(short)nxh2; A[1]=(short)xxh; A[2]=(short)xxl;
        A[3]=ONE; A[4]=ONE; A[5]=0; A[6]=0; A[7]=0;
    }

    f32x16 zacc;
#pragma unroll
    for (int r = 0; r < 16; ++r) zacc[r] = 0.f;
    float rm[16];
#pragma unroll
    for (int r = 0; r < 16; ++r) rm[r] = BIGF;

    const uint4* __restrict__ bfp = bfrag + (size_t)c * NT * 64 + l;

    int t = t0;
    for (; t + 8 <= t1; t += 8){
        // issue all 8 tile loads up-front (independent, stay in flight)
        const bf16x8 T0 = __builtin_bit_cast(bf16x8, bfp[(size_t)(t+0) * 64]);
        const bf16x8 T1 = __builtin_bit_cast(bf16x8, bfp[(size_t)(t+1) * 64]);
        const bf16x8 T2 = __builtin_bit_cast(bf16x8, bfp[(size_t)(t+2) * 64]);
        const bf16x8 T3 = __builtin_bit_cast(bf16x8, bfp[(size_t)(t+3) * 64]);
        const bf16x8 T4 = __builtin_bit_cast(bf16x8, bfp[(size_t)(t+4) * 64]);
        const bf16x8 T5 = __builtin_bit_cast(bf16x8, bfp[(size_t)(t+5) * 64]);
        const bf16x8 T6 = __builtin_bit_cast(bf16x8, bfp[(size_t)(t+6) * 64]);
        const bf16x8 T7 = __builtin_bit_cast(bf16x8, bfp[(size_t)(t+7) * 64]);

        {
            const f32x16 u0 = __builtin_amdgcn_mfma_f32_32x32x16_bf16(A, T0, zacc, 0, 0, 0);
            const f32x16 u1 = __builtin_amdgcn_mfma_f32_32x32x16_bf16(A, T1, zacc, 0, 0, 0);
#pragma unroll
            for (int r = 0; r < 16; ++r) rm[r] = fminf(fminf(rm[r], u0[r]), u1[r]);
        }
        __builtin_amdgcn_sched_barrier(0);   // cap live accumulators at 2
        {
            const f32x16 u2 = __builtin_amdgcn_mfma_f32_32x32x16_bf16(A, T2, zacc, 0, 0, 0);
            const f32x16 u3 = __builtin_amdgcn_mfma_f32_32x32x16_bf16(A, T3, zacc, 0, 0, 0);
#pragma unroll
            for (int r = 0; r < 16; ++r) rm[r] = fminf(fminf(rm[r], u2[r]), u3[r]);
        }
        __builtin_amdgcn_sched_barrier(0);
        {
            const f32x16 u4 = __builtin_amdgcn_mfma_f32_32x32x16_bf16(A, T4, zacc, 0, 0, 0);
            const f32x16 u5 = __builtin_amdgcn_mfma_f32_32x32x16_bf16(A, T5, zacc, 0, 0, 0);
#pragma unroll
            for (int r = 0; r < 16; ++r) rm[r] = fminf(fminf(rm[r], u4[r]), u5[r]);
        }
        __builtin_amdgcn_sched_barrier(0);
        {
            const f32x16 u6 = __builtin_amdgcn_mfma_f32_32x32x16_bf16(A, T6, zacc, 0, 0, 0);
            const f32x16 u7 = __builtin_amdgcn_mfma_f32_32x32x16_bf16(A, T7, zacc, 0, 0, 0);
#pragma unroll
            for (int r = 0; r < 16; ++r) rm[r] = fminf(fminf(rm[r], u6[r]), u7[r]);
        }
        __builtin_amdgcn_sched_barrier(0);
    }
    for (; t < t1; ++t){
        const bf16x8 T0 = __builtin_bit_cast(bf16x8, bfp[(size_t)t * 64]);
        const f32x16 u0 = __builtin_amdgcn_mfma_f32_32x32x16_bf16(A, T0, zacc, 0, 0, 0);
#pragma unroll
        for (int r = 0; r < 16; ++r) rm[r] = fminf(rm[r], u0[r]);
    }

    // row-min butterfly within each 32-lane half (cols live across lanes)
#pragma unroll
    for (int r = 0; r < 16; ++r){
        float v = rm[r];
        v = fminf(v, __shfl_xor(v, 1, 64));
        v = fminf(v, __shfl_xor(v, 2, 64));
        v = fminf(v, __shfl_xor(v, 4, 64));
        v = fminf(v, __shfl_xor(v, 8, 64));
        v = fminf(v, __shfl_xor(v, 16, 64));
        rm[r] = v;
    }
    float* __restrict__ rp = rowpart + (size_t)(c * 4 + blockIdx.y) * RSTRIDE;
#pragma unroll
    for (int r = 0; r < 16; ++r){             // static index only (no scratch)
        if ((l & 31) == r){
            const int rowl = (r & 3) + 8 * (r >> 2) + 4 * h;
            const int gr = blockIdx.x * 128 + w * 32 + rowl;
            if (gr < Np) rp[gr] = rm[r];
        }
    }
}

// edge loss + normal consistency + laplacian cot scatter, one dispatch.
__global__ void mesh_k(const float* __restrict__ pred,
                       const int* __restrict__ edges, int E,
                       const int* __restrict__ pairs, int P,
                       const int* __restrict__ faces, int F,
                       int N, int B, float scaleE, float scaleP,
                       float* __restrict__ Lx, float* __restrict__ rowsum,
                       float* __restrict__ accum)
{
    const int tE = B * E, tP = B * P, tF = B * F;
    const int total = tE + tP + tF;
    float se = 0.f, sp = 0.f;
    for (int idx = blockIdx.x * blockDim.x + threadIdx.x; idx < total;
         idx += gridDim.x * blockDim.x) {
        if (idx < tE) {
            const int b = idx / E;
            const int e = idx - b * E;
            const float* __restrict__ vb = pred + (size_t)b * N * 3;
            const int i0 = edges[e * 2 + 0], i1 = edges[e * 2 + 1];
            float dx = vb[i0 * 3 + 0] - vb[i1 * 3 + 0];
            float dy = vb[i0 * 3 + 1] - vb[i1 * 3 + 1];
            float dz = vb[i0 * 3 + 2] - vb[i1 * 3 + 2];
            se += fmaf(dx, dx, fmaf(dy, dy, dz * dz));
        } else if (idx < tE + tP) {
            const int q = idx - tE;
            const int b = q / P;
            const int p = q - b * P;
            const float* __restrict__ vb = pred + (size_t)b * N * 3;
            const int a0 = pairs[p * 4 + 0], a1 = pairs[p * 4 + 1];
            const int a2 = pairs[p * 4 + 2], a3 = pairs[p * 4 + 3];
            float p0x = vb[a0 * 3], p0y = vb[a0 * 3 + 1], p0z = vb[a0 * 3 + 2];
            float ex = vb[a1 * 3] - p0x, ey = vb[a1 * 3 + 1] - p0y, ez = vb[a1 * 3 + 2] - p0z;
            float ux = vb[a2 * 3] - p0x, uy = vb[a2 * 3 + 1] - p0y, uz = vb[a2 * 3 + 2] - p0z;
            float wx = vb[a3 * 3] - p0x, wy = vb[a3 * 3 + 1] - p0y, wz = vb[a3 * 3 + 2] - p0z;
            float n0x = ey * uz - ez * uy;
            float n0y = ez * ux - ex * uz;
            float n0z = ex * uy - ey * ux;
            float n1x = -(ey * wz - ez * wy);
            float n1y = -(ez * wx - ex * wz);
            float n1z = -(ex * wy - ey * wx);
            float dt = n0x * n1x + n0y * n1y + n0z * n1z;
            float l0 = sqrtf(n0x * n0x + n0y * n0y + n0z * n0z);
            float l1 = sqrtf(n1x * n1x + n1y * n1y + n1z * n1z);
            sp += 1.0f - dt / (fmaxf(l0, 1e-8f) * fmaxf(l1, 1e-8f));
        } else {
            const int q = idx - tE - tP;
            const int b = q / F;
            const int f = q - b * F;
            const float* __restrict__ vb = pred + (size_t)b * N * 3;
            const int i0 = faces[f * 3 + 0], i1 = faces[f * 3 + 1], i2 = faces[f * 3 + 2];
            float v0x = vb[i0 * 3], v0y = vb[i0 * 3 + 1], v0z = vb[i0 * 3 + 2];
            float v1x = vb[i1 * 3], v1y = vb[i1 * 3 + 1], v1z = vb[i1 * 3 + 2];
            float v2x = vb[i2 * 3], v2y = vb[i2 * 3 + 1], v2z = vb[i2 * 3 + 2];
            float ax = v1x - v2x, ay = v1y - v2y, az = v1z - v2z;
            float bx = v0x - v2x, by = v0y - v2y, bz = v0z - v2z;
            float cx = v0x - v1x, cy = v0y - v1y, cz = v0z - v1z;
            float A  = sqrtf(ax * ax + ay * ay + az * az);
            float Bl = sqrtf(bx * bx + by * by + bz * bz);
            float C  = sqrtf(cx * cx + cy * cy + cz * cz);
            float s2 = 0.5f * (A + Bl + C);
            float area = sqrtf(fmaxf(s2 * (s2 - A) * (s2 - Bl) * (s2 - C), 1e-12f));
            float A2 = A * A, B2 = Bl * Bl, C2 = C * C;
            float inv4a = 1.0f / (4.0f * area);
            float cota = (B2 + C2 - A2) * inv4a;
            float cotb = (A2 + C2 - B2) * inv4a;
            float cotc = (A2 + B2 - C2) * inv4a;

            float* __restrict__ Lb = Lx + (size_t)b * N * 3;
            float* __restrict__ rb = rowsum + (size_t)b * N;
            #define SCAT(i, j, wv)                                            \
                atomicAdd(&Lb[(i) * 3 + 0], (wv) * vb[(j) * 3 + 0]);          \
                atomicAdd(&Lb[(i) * 3 + 1], (wv) * vb[(j) * 3 + 1]);          \
                atomicAdd(&Lb[(i) * 3 + 2], (wv) * vb[(j) * 3 + 2]);          \
                atomicAdd(&rb[(i)], (wv));
            SCAT(i1, i2, cota) SCAT(i2, i1, cota)
            SCAT(i2, i0, cotb) SCAT(i0, i2, cotb)
            SCAT(i0, i1, cotc) SCAT(i1, i0, cotc)
            #undef SCAT
        }
    }
    se = wave_sum(se);
    sp = wave_sum(sp);
    if ((threadIdx.x & 63) == 0) atomicAdd(accum, fmaf(se, scaleE, sp * scaleP));
}

// rowpart 4-chunk min + clamp + lap residual, one dispatch.
__global__ void finalize_k(const float* __restrict__ rowpart,
                           const float* __restrict__ pred, const float* __restrict__ Lx,
                           const float* __restrict__ rowsum,
                           int N, float sMain, float sVel, float scaleL,
                           float* __restrict__ accum)
{
    const int total = 8 * N + 2 * N;
    float sm = 0.f, sv = 0.f, sl = 0.f;
    for (int idx = blockIdx.x * blockDim.x + threadIdx.x; idx < total;
         idx += gridDim.x * blockDim.x) {
        if (idx < 8 * N) {
            const int c = idx / N, i = idx - c * N;
            const int ds = (c >> 1) & 1;
            if (i < N - ds) {
                const float* rp = rowpart + (size_t)c * 4 * RSTRIDE;
                float v = fminf(fminf(rp[i], rp[RSTRIDE + i]),
                                fminf(rp[2*RSTRIDE + i], rp[3*RSTRIDE + i]));
                float d = fmaxf(v, 0.f);
                if (ds) sv += d; else sm += d;
            }
        } else {
            const int q = idx - 8 * N;       // B*N lap entries
            float rs = rowsum[q];
            float nw = rs > 0.f ? 1.0f / rs : 0.f;
            float rx = Lx[q*3+0]*nw - pred[q*3+0];
            float ry = Lx[q*3+1]*nw - pred[q*3+1];
            float rz = Lx[q*3+2]*nw - pred[q*3+2];
            sl += sqrtf(rx*rx + ry*ry + rz*rz);
        }
    }
    sm = wave_sum(sm); sv = wave_sum(sv); sl = wave_sum(sl);
    if ((threadIdx.x & 63) == 0)
        atomicAdd(accum, fmaf(sm, sMain, fmaf(sv, sVel, sl * scaleL)));
}

__global__ void write_out_k(const float* __restrict__ accum, float* __restrict__ out)
{
    out[0] = accum[0];
}

extern "C" void kernel_launch(void* const* d_in, const int* in_sizes, int n_in,
                              void* d_out, int out_size, void* d_ws, size_t ws_size,
                              hipStream_t stream)
{
    const float* pred = (const float*)d_in[0];
    const float* tgt  = (const float*)d_in[1];
    const int* faces  = (const int*)d_in[2];
    const int* edges  = (const int*)d_in[3];
    const int* pairs  = (const int*)d_in[4];

    const int B = 2;
    const int N = in_sizes[0] / (3 * B);   // 8281
    const int F = in_sizes[2] / 3;
    const int E = in_sizes[3] / 2;
    const int P = in_sizes[4] / 4;
    const int NT = (N + 31) >> 5;          // 259

    // workspace layout (4B units):
    // [accum 8][Lx B*N*3][rowsum B*N][rowpart 8*4*RSTRIDE][bfrag 8*NT*64 u4]
    float* ws      = (float*)d_ws;
    float* accum   = ws;
    float* Lx      = ws + 8;
    float* rowsum  = Lx + (size_t)B * N * 3;
    float* rowpart = rowsum + (size_t)B * N;
    size_t off     = 8 + (size_t)B*N*3 + (size_t)B*N + (size_t)32*RSTRIDE;
    uint4* bfrag   = (uint4*)(ws + off);   // off*4 16B-aligned (off div by 4)

    const int nzero = 8 + B * N * 3 + B * N;

    bprep_k<<<dim3((8 * NT + 3) / 4), dim3(256), 0, stream>>>(pred, tgt, N, bfrag,
                                                              ws, nzero);

    chamfer_mfma_k<<<dim3((N + 127) / 128, 4, 8), dim3(256), 0, stream>>>(
        pred, tgt, N, bfrag, rowpart);

    mesh_k<<<128, dim3(256), 0, stream>>>(pred, edges, E, pairs, P, faces, F, N, B,
                                          W_EDGE / ((float)B * (float)E),
                                          W_NORMAL / ((float)B * (float)P),
                                          Lx, rowsum, accum);

    finalize_k<<<96, dim3(256), 0, stream>>>(rowpart, pred, Lx, rowsum, N,
                                             1.0f / ((float)B * (float)N),
                                             W_VEL / ((float)B * (float)(N - 1)),
                                             W_LAP / ((float)B * (float)N), accum);

    write_out_k<<<1, 1, 0, stream>>>(accum, (float*)d_out);
}